// Round 10
// baseline (28.715 us; speedup 1.0000x reference)
//
#include <hip/hip_runtime.h>
#include <math.h>
#include <float.h>

#define BB 16
#define NN 2382
#define TOT 38112           // BB*NN
#define NV4 9528            // TOT/4
#define EPSF 1e-5f
#define L2E 1.4426950408889634f
#define TT 32               // G-table nodes per batch
#define PITER 16
#define NB_OUT 149          // ceil(TOT/256)

// ws float layout
#define WS_QR   0           // float2[TOT] {q, r}
#define WS_TAB  76288       // 16*32
#define WS_META 76800       // 16*2 {qmin, qinv}
#define WS_MOM  76864       // 16*5 {sG, sG2, sRG, sR, sR2}

// 16 blocks (one per batch) x 1024: z-stats (redundant), power-iter, KPQR
// into LDS (QR written through to ws), ranges, TT-node G table, moments.
__global__ __launch_bounds__(1024) void kA_table(
    const float* __restrict__ z,  const float* __restrict__ w1,
    const float* __restrict__ g1, const float* __restrict__ be1,
    const float* __restrict__ wq, const float* __restrict__ bqp,
    const float* __restrict__ wk, const float* __restrict__ bkp,
    const float* __restrict__ wv, const float* __restrict__ bv,
    const float* __restrict__ w2, const float* __restrict__ b2p,
    float* __restrict__ ws)
{
    __shared__ float2 sKP[NN];      // {K[m], P[m]}
    __shared__ float2 sQR[NN];      // {q[n], r[n]}
    __shared__ float  sG[TT];
    __shared__ float  sred[96];
    const int tid = threadIdx.x;
    const int wave = tid >> 6, lane = tid & 63;
    const int b = blockIdx.x;

    // ---------- z stats (redundant per block; 9.3 float4/thread) ------------
    const float4* __restrict__ z4 = (const float4*)z;
    float s = 0.f, s2 = 0.f;
    for (int i = tid; i < NV4; i += 1024) {
        const float4 v = z4[i];
        s += v.x + v.y + v.z + v.w;
        s2 = fmaf(v.x,v.x, fmaf(v.y,v.y, fmaf(v.z,v.z, fmaf(v.w,v.w, s2))));
    }
    #pragma unroll
    for (int off = 32; off; off >>= 1) {
        s  += __shfl_xor(s, off);
        s2 += __shfl_xor(s2, off);
    }
    if (lane == 0) { sred[wave] = s; sred[16+wave] = s2; }
    __syncthreads();
    const float invn = 1.f/(float)TOT;
    float zs = 0.f, zq = 0.f;
    #pragma unroll
    for (int j = 0; j < 16; ++j) { zs += sred[j]; zq += sred[16+j]; }
    const float mz = zs*invn;
    const float vz = zq*invn - mz*mz;
    __syncthreads();   // sred reused

    // ---------- wave-parallel power iteration on M = wv^T wv ----------------
    const int pi = lane >> 3, pj = lane & 7;
    float Mij = 0.f;
    #pragma unroll
    for (int o = 0; o < 8; ++o) Mij = fmaf(wv[o*8+pi], wv[o*8+pj], Mij);
    float u = 1.f, nr = 1.f;
    for (int it = 0; it < PITER; ++it) {
        float a = Mij*u;
        a += __shfl_xor(a,1); a += __shfl_xor(a,2); a += __shfl_xor(a,4);
        float bb = a*a;
        bb += __shfl_xor(bb,8); bb += __shfl_xor(bb,16); bb += __shfl_xor(bb,32);
        nr = sqrtf(bb);
        u = __shfl(a, pj<<3) / nr;
    }
    const float invsig = rsqrtf(nr);    // 1/sigma_max(wv)

    // ---------- derived params ----------------------------------------------
    float n1=0.f, nq=0.f, nk=0.f, n2=0.f;
    #pragma unroll
    for (int h=0; h<8; ++h) {
        n1 = fmaf(w1[h], w1[h], n1);
        nq = fmaf(wq[h], wq[h], nq);
        nk = fmaf(wk[h], wk[h], nk);
        n2 = fmaf(w2[h], w2[h], n2);
    }
    n1 = sqrtf(n1); nq = sqrtf(nq); nk = sqrtf(nk); n2 = sqrtf(n2);

    float a1[8], c1[8], wqn[8], wkn[8], w2n[8], wvP[8];
    #pragma unroll
    for (int h=0; h<8; ++h) {
        const float w1n = w1[h]/n1;
        const float rs = rsqrtf(fmaf(w1n*w1n, vz, EPSF));
        a1[h]  = w1n * rs * g1[h];          // x_h = relu(a1*z + c1)
        c1[h]  = be1[h] - mz*a1[h];         // b1 cancels in train-mode BN
        wqn[h] = wq[h]/nq;
        wkn[h] = wk[h]/nk;
        w2n[h] = w2[h]/n2;
    }
    float bvP = 0.f;
    #pragma unroll
    for (int h=0; h<8; ++h) bvP = fmaf(w2n[h], bv[h], bvP);
    #pragma unroll
    for (int c=0; c<8; ++c) {
        float a = 0.f;
        #pragma unroll
        for (int h=0; h<8; ++h) a = fmaf(w2n[h], wv[h*8+c], a);
        wvP[c] = a * invsig;
    }
    const float bq = bqp[0], bk = bkp[0], b2 = b2p[0];

    // ---------- KPQR into LDS (QR write-through to ws); ranges --------------
    const float* __restrict__ zb = z + b*NN;
    float2* __restrict__ qr_out = (float2*)(ws + WS_QR);
    float lkmax=-FLT_MAX, lkmin=FLT_MAX, lqmax=-FLT_MAX, lqmin=FLT_MAX;
    for (int m = tid; m < NN; m += 1024) {
        const float zv = zb[m];
        float xh[8];
        #pragma unroll
        for (int h=0;h<8;++h) xh[h] = fmaxf(fmaf(a1[h], zv, c1[h]), 0.f);
        float kk = bk, pp = bvP, qq = bq, rr = b2;
        #pragma unroll
        for (int h=0;h<8;++h) {
            kk = fmaf(wkn[h], xh[h], kk);
            pp = fmaf(wvP[h], xh[h], pp);
            qq = fmaf(wqn[h], xh[h], qq);
            rr = fmaf(w2n[h], xh[h], rr);
        }
        sKP[m] = make_float2(kk, pp);
        sQR[m] = make_float2(qq, rr);
        qr_out[b*NN + m] = make_float2(qq, rr);
        lkmax = fmaxf(lkmax, kk); lkmin = fminf(lkmin, kk);
        lqmax = fmaxf(lqmax, qq); lqmin = fminf(lqmin, qq);
    }
    #pragma unroll
    for (int off=32; off; off>>=1) {
        lkmax = fmaxf(lkmax, __shfl_xor(lkmax, off));
        lkmin = fminf(lkmin, __shfl_xor(lkmin, off));
        lqmax = fmaxf(lqmax, __shfl_xor(lqmax, off));
        lqmin = fminf(lqmin, __shfl_xor(lqmin, off));
    }
    if (lane == 0) {
        sred[wave] = lkmax; sred[16+wave] = lkmin;
        sred[32+wave] = lqmax; sred[48+wave] = lqmin;
    }
    __syncthreads();
    float kmax=-FLT_MAX, kmin=FLT_MAX, qmax=-FLT_MAX, qmin=FLT_MAX;
    #pragma unroll
    for (int j=0; j<16; ++j) {
        kmax = fmaxf(kmax, sred[j]);    kmin = fminf(kmin, sred[16+j]);
        qmax = fmaxf(qmax, sred[32+j]); qmin = fminf(qmin, sred[48+j]);
    }

    // ---------- G table: node = tid>>5, sub = tid&31, m = sub+32j -----------
    const int node = tid >> 5, sub = tid & 31;
    const float xq = fmaf((qmax-qmin), (float)node*(1.f/(float)(TT-1)), qmin);
    const float st = fmaxf(xq*kmax, xq*kmin);   // max_m xq*K[m]
    const float x2 = xq*L2E, st2 = st*L2E;
    float den = 0.f, num = 0.f;
    for (int m = sub; m < NN; m += 32) {
        const float2 kp = sKP[m];
        const float e = __builtin_amdgcn_exp2f(fmaf(x2, kp.x, -st2));
        den += e; num = fmaf(e, kp.y, num);
    }
    #pragma unroll
    for (int off=1; off<32; off<<=1) {          // stays within 32-lane half
        den += __shfl_xor(den, off);
        num += __shfl_xor(num, off);
    }
    const float gnode = num/den;                // den >= 1 (shifted)
    if (sub == 0) {
        sG[node] = gnode;
        ws[WS_TAB + b*TT + node] = gnode;
    }
    __syncthreads();

    // ---------- analytic BN2 moments (<=3 lerps/thread) ---------------------
    const float qinv = (qmax > qmin) ? (float)(TT-1)/(qmax-qmin) : 0.f;
    float mG=0.f, mG2=0.f, mRG=0.f, mR=0.f, mR2=0.f;
    for (int n = tid; n < NN; n += 1024) {
        const float2 qr = sQR[n];
        float uu = fminf(fmaxf((qr.x - qmin)*qinv, 0.f), (float)(TT-1));
        int i = (int)uu; if (i > TT-2) i = TT-2;
        const float f = uu - (float)i;
        const float g = fmaf(f, sG[i+1]-sG[i], sG[i]);
        mG += g;            mG2 = fmaf(g, g, mG2);
        mRG = fmaf(qr.y, g, mRG);
        mR += qr.y;         mR2 = fmaf(qr.y, qr.y, mR2);
    }
    #pragma unroll
    for (int off=32; off; off>>=1) {
        mG  += __shfl_xor(mG,  off);
        mG2 += __shfl_xor(mG2, off);
        mRG += __shfl_xor(mRG, off);
        mR  += __shfl_xor(mR,  off);
        mR2 += __shfl_xor(mR2, off);
    }
    if (lane == 0) {
        sred[wave] = mG;     sred[16+wave] = mG2;  sred[32+wave] = mRG;
        sred[48+wave] = mR;  sred[64+wave] = mR2;
    }
    __syncthreads();
    if (tid == 0) {
        float tG=0.f, tG2=0.f, tRG=0.f, tR=0.f, tR2=0.f;
        #pragma unroll
        for (int j=0; j<16; ++j) {
            tG += sred[j]; tG2 += sred[16+j]; tRG += sred[32+j];
            tR += sred[48+j]; tR2 += sred[64+j];
        }
        ws[WS_MOM + b*5 + 0] = tG;
        ws[WS_MOM + b*5 + 1] = tG2;
        ws[WS_MOM + b*5 + 2] = tRG;
        ws[WS_MOM + b*5 + 3] = tR;
        ws[WS_MOM + b*5 + 4] = tR2;
        ws[WS_META + b*2]     = qmin;
        ws[WS_META + b*2 + 1] = qinv;
    }
}

// 149 blocks x 256: global stats from 80 uniform moment floats (fixed order),
// per-item lerp from ws table + BN2 + ReLU -> out.
__global__ __launch_bounds__(256) void kB_out(
    const float* __restrict__ ws, const float* __restrict__ gammap,
    const float* __restrict__ g2, const float* __restrict__ be2,
    float* __restrict__ out)
{
    const float gamma = gammap[0];
    float sy = 0.f, sy2 = 0.f;
    #pragma unroll
    for (int j = 0; j < BB; ++j) {              // fixed order, uniform loads
        const float tG  = ws[WS_MOM + j*5 + 0];
        const float tG2 = ws[WS_MOM + j*5 + 1];
        const float tRG = ws[WS_MOM + j*5 + 2];
        const float tR  = ws[WS_MOM + j*5 + 3];
        const float tR2 = ws[WS_MOM + j*5 + 4];
        sy  += tR + gamma*tG;
        sy2 += tR2 + 2.f*gamma*tRG + gamma*gamma*tG2;
    }
    const float invn = 1.f/(float)TOT;
    const float my = sy*invn;
    const float vy = sy2*invn - my*my;
    const float sc = g2[0]*rsqrtf(vy + EPSF);
    const float sh = be2[0] - my*sc;

    const int item = blockIdx.x*256 + threadIdx.x;
    if (item >= TOT) return;
    const int b = item / NN;
    const float2 qr = ((const float2*)(ws + WS_QR))[item];
    const float qmin = ws[WS_META + b*2], qinv = ws[WS_META + b*2 + 1];
    float uu = fminf(fmaxf((qr.x - qmin)*qinv, 0.f), (float)(TT-1));
    int i = (int)uu; if (i > TT-2) i = TT-2;
    const float f = uu - (float)i;
    const float g0 = ws[WS_TAB + b*TT + i];
    const float g1v = ws[WS_TAB + b*TT + i + 1];
    const float y = qr.y + gamma*fmaf(f, g1v-g0, g0);
    out[item] = fmaxf(fmaf(y, sc, sh), 0.f);
}

extern "C" void kernel_launch(void* const* d_in, const int* in_sizes, int n_in,
                              void* d_out, int out_size, void* d_ws, size_t ws_size,
                              hipStream_t stream)
{
    const float* z    = (const float*)d_in[0];
    const float* w1   = (const float*)d_in[1];
    // d_in[2] = b1 (cancels in train-mode BN1)
    const float* g1   = (const float*)d_in[3];
    const float* be1  = (const float*)d_in[4];
    const float* wq   = (const float*)d_in[5];
    const float* bq   = (const float*)d_in[6];
    const float* wk   = (const float*)d_in[7];
    const float* bk   = (const float*)d_in[8];
    const float* wv   = (const float*)d_in[9];
    const float* bv   = (const float*)d_in[10];
    const float* gamma= (const float*)d_in[11];
    const float* w2   = (const float*)d_in[12];
    const float* b2   = (const float*)d_in[13];
    const float* g2   = (const float*)d_in[14];
    const float* be2  = (const float*)d_in[15];
    float* ws  = (float*)d_ws;
    float* out = (float*)d_out;

    kA_table<<<BB, 1024, 0, stream>>>(
        z, w1, g1, be1, wq, bq, wk, bk, wv, bv, w2, b2, ws);

    kB_out<<<NB_OUT, 256, 0, stream>>>(ws, gamma, g2, be2, out);
}

// Round 11
// 27.792 us; speedup vs baseline: 1.0332x; 1.0332x over previous
//
#include <hip/hip_runtime.h>
#include <math.h>
#include <float.h>

#define BB 16
#define NN 2382
#define TOT 38112           // BB*NN
#define NV4 9528            // TOT/4
#define EPSF 1e-5f
#define L2E 1.4426950408889634f
#define TT 32               // G-table nodes per batch
#define PITER 16
#define NB_OUT 149          // ceil(TOT/256)

// ws float layout
#define WS_QR   0           // float2[TOT] {q, r}
#define WS_TAB  76288       // 16*32
#define WS_META 76800       // 16*2 {qmin, qinv}
#define WS_MOM  76864       // 16*5 {sG, sG2, sRG, sR, sR2}

// 16 blocks (one per batch) x 1024: z-stats (redundant), power-iter, KPQR
// into LDS (QR written through to ws), ranges, TT-node G table (4-way
// latency-unrolled), analytic BN2 moments.
__global__ __launch_bounds__(1024) void kA_table(
    const float* __restrict__ z,  const float* __restrict__ w1,
    const float* __restrict__ g1, const float* __restrict__ be1,
    const float* __restrict__ wq, const float* __restrict__ bqp,
    const float* __restrict__ wk, const float* __restrict__ bkp,
    const float* __restrict__ wv, const float* __restrict__ bv,
    const float* __restrict__ w2, const float* __restrict__ b2p,
    float* __restrict__ ws)
{
    __shared__ float2 sKP[NN];      // {K[m], P[m]}
    __shared__ float2 sQR[NN];      // {q[n], r[n]}
    __shared__ float  sG[TT];
    __shared__ float  sred[96];
    const int tid = threadIdx.x;
    const int wave = tid >> 6, lane = tid & 63;
    const int b = blockIdx.x;

    // ---------- z stats (redundant per block; 9.3 float4/thread) ------------
    const float4* __restrict__ z4 = (const float4*)z;
    float s = 0.f, s2 = 0.f;
    for (int i = tid; i < NV4; i += 1024) {
        const float4 v = z4[i];
        s += v.x + v.y + v.z + v.w;
        s2 = fmaf(v.x,v.x, fmaf(v.y,v.y, fmaf(v.z,v.z, fmaf(v.w,v.w, s2))));
    }
    #pragma unroll
    for (int off = 32; off; off >>= 1) {
        s  += __shfl_xor(s, off);
        s2 += __shfl_xor(s2, off);
    }
    if (lane == 0) { sred[wave] = s; sred[16+wave] = s2; }
    __syncthreads();
    const float invn = 1.f/(float)TOT;
    float zs = 0.f, zq = 0.f;
    #pragma unroll
    for (int j = 0; j < 16; ++j) { zs += sred[j]; zq += sred[16+j]; }
    const float mz = zs*invn;
    const float vz = zq*invn - mz*mz;
    __syncthreads();   // sred reused

    // ---------- wave-parallel power iteration on M = wv^T wv ----------------
    const int pi = lane >> 3, pj = lane & 7;
    float Mij = 0.f;
    #pragma unroll
    for (int o = 0; o < 8; ++o) Mij = fmaf(wv[o*8+pi], wv[o*8+pj], Mij);
    float u = 1.f, nr = 1.f;
    for (int it = 0; it < PITER; ++it) {
        float a = Mij*u;
        a += __shfl_xor(a,1); a += __shfl_xor(a,2); a += __shfl_xor(a,4);
        float bb = a*a;
        bb += __shfl_xor(bb,8); bb += __shfl_xor(bb,16); bb += __shfl_xor(bb,32);
        nr = sqrtf(bb);
        u = __shfl(a, pj<<3) / nr;
    }
    const float invsig = rsqrtf(nr);    // 1/sigma_max(wv)

    // ---------- derived params ----------------------------------------------
    float n1=0.f, nq=0.f, nk=0.f, n2=0.f;
    #pragma unroll
    for (int h=0; h<8; ++h) {
        n1 = fmaf(w1[h], w1[h], n1);
        nq = fmaf(wq[h], wq[h], nq);
        nk = fmaf(wk[h], wk[h], nk);
        n2 = fmaf(w2[h], w2[h], n2);
    }
    n1 = sqrtf(n1); nq = sqrtf(nq); nk = sqrtf(nk); n2 = sqrtf(n2);

    float a1[8], c1[8], wqn[8], wkn[8], w2n[8], wvP[8];
    #pragma unroll
    for (int h=0; h<8; ++h) {
        const float w1n = w1[h]/n1;
        const float rs = rsqrtf(fmaf(w1n*w1n, vz, EPSF));
        a1[h]  = w1n * rs * g1[h];          // x_h = relu(a1*z + c1)
        c1[h]  = be1[h] - mz*a1[h];         // b1 cancels in train-mode BN
        wqn[h] = wq[h]/nq;
        wkn[h] = wk[h]/nk;
        w2n[h] = w2[h]/n2;
    }
    float bvP = 0.f;
    #pragma unroll
    for (int h=0; h<8; ++h) bvP = fmaf(w2n[h], bv[h], bvP);
    #pragma unroll
    for (int c=0; c<8; ++c) {
        float a = 0.f;
        #pragma unroll
        for (int h=0; h<8; ++h) a = fmaf(w2n[h], wv[h*8+c], a);
        wvP[c] = a * invsig;
    }
    const float bq = bqp[0], bk = bkp[0], b2 = b2p[0];

    // ---------- KPQR into LDS (QR write-through to ws); ranges --------------
    const float* __restrict__ zb = z + b*NN;
    float2* __restrict__ qr_out = (float2*)(ws + WS_QR);
    float lkmax=-FLT_MAX, lkmin=FLT_MAX, lqmax=-FLT_MAX, lqmin=FLT_MAX;
    for (int m = tid; m < NN; m += 1024) {
        const float zv = zb[m];
        float xh[8];
        #pragma unroll
        for (int h=0;h<8;++h) xh[h] = fmaxf(fmaf(a1[h], zv, c1[h]), 0.f);
        float kk = bk, pp = bvP, qq = bq, rr = b2;
        #pragma unroll
        for (int h=0;h<8;++h) {
            kk = fmaf(wkn[h], xh[h], kk);
            pp = fmaf(wvP[h], xh[h], pp);
            qq = fmaf(wqn[h], xh[h], qq);
            rr = fmaf(w2n[h], xh[h], rr);
        }
        sKP[m] = make_float2(kk, pp);
        sQR[m] = make_float2(qq, rr);
        qr_out[b*NN + m] = make_float2(qq, rr);
        lkmax = fmaxf(lkmax, kk); lkmin = fminf(lkmin, kk);
        lqmax = fmaxf(lqmax, qq); lqmin = fminf(lqmin, qq);
    }
    #pragma unroll
    for (int off=32; off; off>>=1) {
        lkmax = fmaxf(lkmax, __shfl_xor(lkmax, off));
        lkmin = fminf(lkmin, __shfl_xor(lkmin, off));
        lqmax = fmaxf(lqmax, __shfl_xor(lqmax, off));
        lqmin = fminf(lqmin, __shfl_xor(lqmin, off));
    }
    if (lane == 0) {
        sred[wave] = lkmax; sred[16+wave] = lkmin;
        sred[32+wave] = lqmax; sred[48+wave] = lqmin;
    }
    __syncthreads();
    float kmax=-FLT_MAX, kmin=FLT_MAX, qmax=-FLT_MAX, qmin=FLT_MAX;
    #pragma unroll
    for (int j=0; j<16; ++j) {
        kmax = fmaxf(kmax, sred[j]);    kmin = fminf(kmin, sred[16+j]);
        qmax = fmaxf(qmax, sred[32+j]); qmin = fminf(qmin, sred[48+j]);
    }

    // ---------- G table: node = tid>>5, sub = tid&31 ------------------------
    // 4-way latency unroll: 4 independent {ds_read, exp, fma} chains.
    const int node = tid >> 5, sub = tid & 31;
    const float xq = fmaf((qmax-qmin), (float)node*(1.f/(float)(TT-1)), qmin);
    const float st = fmaxf(xq*kmax, xq*kmin);   // max_m xq*K[m]
    const float x2 = xq*L2E, st2 = st*L2E;
    float den0=0.f, num0=0.f, den1=0.f, num1=0.f;
    float den2=0.f, num2=0.f, den3=0.f, num3=0.f;
    int m = sub;
    #pragma unroll 2
    for (int t = 0; t < 18; ++t, m += 128) {     // 18*128 = 2304 <= NN-96-31
        const float2 kp0 = sKP[m];
        const float2 kp1 = sKP[m+32];
        const float2 kp2 = sKP[m+64];
        const float2 kp3 = sKP[m+96];
        const float e0 = __builtin_amdgcn_exp2f(fmaf(x2, kp0.x, -st2));
        const float e1 = __builtin_amdgcn_exp2f(fmaf(x2, kp1.x, -st2));
        const float e2 = __builtin_amdgcn_exp2f(fmaf(x2, kp2.x, -st2));
        const float e3 = __builtin_amdgcn_exp2f(fmaf(x2, kp3.x, -st2));
        den0 += e0; num0 = fmaf(e0, kp0.y, num0);
        den1 += e1; num1 = fmaf(e1, kp1.y, num1);
        den2 += e2; num2 = fmaf(e2, kp2.y, num2);
        den3 += e3; num3 = fmaf(e3, kp3.y, num3);
    }
    for (; m < NN; m += 32) {                    // tail: 2304+sub .. NN-1
        const float2 kp = sKP[m];
        const float e = __builtin_amdgcn_exp2f(fmaf(x2, kp.x, -st2));
        den0 += e; num0 = fmaf(e, kp.y, num0);
    }
    float den = (den0+den1) + (den2+den3);
    float num = (num0+num1) + (num2+num3);
    #pragma unroll
    for (int off=1; off<32; off<<=1) {           // stays within 32-lane half
        den += __shfl_xor(den, off);
        num += __shfl_xor(num, off);
    }
    const float gnode = num/den;                 // den >= 1 (shifted)
    if (sub == 0) {
        sG[node] = gnode;
        ws[WS_TAB + b*TT + node] = gnode;
    }
    __syncthreads();

    // ---------- analytic BN2 moments (<=3 lerps/thread) ---------------------
    const float qinv = (qmax > qmin) ? (float)(TT-1)/(qmax-qmin) : 0.f;
    float mG=0.f, mG2=0.f, mRG=0.f, mR=0.f, mR2=0.f;
    for (int n = tid; n < NN; n += 1024) {
        const float2 qr = sQR[n];
        float uu = fminf(fmaxf((qr.x - qmin)*qinv, 0.f), (float)(TT-1));
        int i = (int)uu; if (i > TT-2) i = TT-2;
        const float f = uu - (float)i;
        const float g = fmaf(f, sG[i+1]-sG[i], sG[i]);
        mG += g;            mG2 = fmaf(g, g, mG2);
        mRG = fmaf(qr.y, g, mRG);
        mR += qr.y;         mR2 = fmaf(qr.y, qr.y, mR2);
    }
    #pragma unroll
    for (int off=32; off; off>>=1) {
        mG  += __shfl_xor(mG,  off);
        mG2 += __shfl_xor(mG2, off);
        mRG += __shfl_xor(mRG, off);
        mR  += __shfl_xor(mR,  off);
        mR2 += __shfl_xor(mR2, off);
    }
    if (lane == 0) {
        sred[wave] = mG;     sred[16+wave] = mG2;  sred[32+wave] = mRG;
        sred[48+wave] = mR;  sred[64+wave] = mR2;
    }
    __syncthreads();
    if (tid == 0) {
        float tG=0.f, tG2=0.f, tRG=0.f, tR=0.f, tR2=0.f;
        #pragma unroll
        for (int j=0; j<16; ++j) {
            tG += sred[j]; tG2 += sred[16+j]; tRG += sred[32+j];
            tR += sred[48+j]; tR2 += sred[64+j];
        }
        ws[WS_MOM + b*5 + 0] = tG;
        ws[WS_MOM + b*5 + 1] = tG2;
        ws[WS_MOM + b*5 + 2] = tRG;
        ws[WS_MOM + b*5 + 3] = tR;
        ws[WS_MOM + b*5 + 4] = tR2;
        ws[WS_META + b*2]     = qmin;
        ws[WS_META + b*2 + 1] = qinv;
    }
}

// 149 blocks x 256: global stats from 80 uniform moment floats (fixed order),
// per-item lerp from ws table + BN2 + ReLU -> out.
__global__ __launch_bounds__(256) void kB_out(
    const float* __restrict__ ws, const float* __restrict__ gammap,
    const float* __restrict__ g2, const float* __restrict__ be2,
    float* __restrict__ out)
{
    const float gamma = gammap[0];
    float sy = 0.f, sy2 = 0.f;
    #pragma unroll
    for (int j = 0; j < BB; ++j) {              // fixed order, uniform loads
        const float tG  = ws[WS_MOM + j*5 + 0];
        const float tG2 = ws[WS_MOM + j*5 + 1];
        const float tRG = ws[WS_MOM + j*5 + 2];
        const float tR  = ws[WS_MOM + j*5 + 3];
        const float tR2 = ws[WS_MOM + j*5 + 4];
        sy  += tR + gamma*tG;
        sy2 += tR2 + 2.f*gamma*tRG + gamma*gamma*tG2;
    }
    const float invn = 1.f/(float)TOT;
    const float my = sy*invn;
    const float vy = sy2*invn - my*my;
    const float sc = g2[0]*rsqrtf(vy + EPSF);
    const float sh = be2[0] - my*sc;

    const int item = blockIdx.x*256 + threadIdx.x;
    if (item >= TOT) return;
    const int b = item / NN;
    const float2 qr = ((const float2*)(ws + WS_QR))[item];
    const float qmin = ws[WS_META + b*2], qinv = ws[WS_META + b*2 + 1];
    float uu = fminf(fmaxf((qr.x - qmin)*qinv, 0.f), (float)(TT-1));
    int i = (int)uu; if (i > TT-2) i = TT-2;
    const float f = uu - (float)i;
    const float g0 = ws[WS_TAB + b*TT + i];
    const float g1v = ws[WS_TAB + b*TT + i + 1];
    const float y = qr.y + gamma*fmaf(f, g1v-g0, g0);
    out[item] = fmaxf(fmaf(y, sc, sh), 0.f);
}

extern "C" void kernel_launch(void* const* d_in, const int* in_sizes, int n_in,
                              void* d_out, int out_size, void* d_ws, size_t ws_size,
                              hipStream_t stream)
{
    const float* z    = (const float*)d_in[0];
    const float* w1   = (const float*)d_in[1];
    // d_in[2] = b1 (cancels in train-mode BN1)
    const float* g1   = (const float*)d_in[3];
    const float* be1  = (const float*)d_in[4];
    const float* wq   = (const float*)d_in[5];
    const float* bq   = (const float*)d_in[6];
    const float* wk   = (const float*)d_in[7];
    const float* bk   = (const float*)d_in[8];
    const float* wv   = (const float*)d_in[9];
    const float* bv   = (const float*)d_in[10];
    const float* gamma= (const float*)d_in[11];
    const float* w2   = (const float*)d_in[12];
    const float* b2   = (const float*)d_in[13];
    const float* g2   = (const float*)d_in[14];
    const float* be2  = (const float*)d_in[15];
    float* ws  = (float*)d_ws;
    float* out = (float*)d_out;

    kA_table<<<BB, 1024, 0, stream>>>(
        z, w1, g1, be1, wq, bq, wk, bk, wv, bv, w2, b2, ws);

    kB_out<<<NB_OUT, 256, 0, stream>>>(ws, gamma, g2, be2, out);
}